// Round 1
// baseline (779.780 us; speedup 1.0000x reference)
//
#include <hip/hip_runtime.h>
#include <hip/hip_bf16.h>
#include <stdint.h>

#define DMODEL 1024
#define NEXP   8
#define HSZ    4096
#define NTOK   4096   // B*S

typedef __attribute__((ext_vector_type(8))) short bf16x8;
typedef __attribute__((ext_vector_type(4))) float f32x4;

// fp32 -> bf16 round-to-nearest (no tie-to-even; bias negligible vs 1.9e-2 tol)
__device__ __forceinline__ unsigned short f2bf(float f) {
  union { float f; unsigned u; } v; v.f = f;
  return (unsigned short)((v.u + 0x8000u) >> 16);
}

// ---------------- router: logits -> softmax -> top2 -> per-expert lists ----
__global__ void router_kernel(const float* __restrict__ x,
                              const float* __restrict__ gw,
                              int* __restrict__ cnt,
                              int* __restrict__ tokl,
                              float* __restrict__ twgt) {
  int t = blockIdx.x;
  int lane = threadIdx.x;  // 64 threads = 1 wave
  const float* xr = x + (size_t)t * DMODEL;
  float acc[NEXP];
#pragma unroll
  for (int e = 0; e < NEXP; ++e) acc[e] = 0.f;
  for (int d = lane; d < DMODEL; d += 64) {
    float xv = xr[d];
#pragma unroll
    for (int e = 0; e < NEXP; ++e) acc[e] = fmaf(xv, gw[e * DMODEL + d], acc[e]);
  }
#pragma unroll
  for (int e = 0; e < NEXP; ++e) {
#pragma unroll
    for (int o = 32; o > 0; o >>= 1) acc[e] += __shfl_down(acc[e], o);
  }
  if (lane == 0) {
    float m = acc[0];
#pragma unroll
    for (int e = 1; e < NEXP; ++e) m = fmaxf(m, acc[e]);
    float p[NEXP]; float s = 0.f;
#pragma unroll
    for (int e = 0; e < NEXP; ++e) { p[e] = __expf(acc[e] - m); s += p[e]; }
    float inv = 1.f / s;
    int i0 = 0; float b0 = p[0];
#pragma unroll
    for (int e = 1; e < NEXP; ++e) if (p[e] > b0) { b0 = p[e]; i0 = e; }
    int i1 = (i0 == 0) ? 1 : 0; float b1v = p[i1];
#pragma unroll
    for (int e = 0; e < NEXP; ++e) if (e != i0 && p[e] > b1v) { b1v = p[e]; i1 = e; }
    int p0 = atomicAdd(&cnt[i0], 1);
    tokl[i0 * NTOK + p0] = t; twgt[i0 * NTOK + p0] = b0 * inv;
    int p1 = atomicAdd(&cnt[i1], 1);
    tokl[i1 * NTOK + p1] = t; twgt[i1 * NTOK + p1] = b1v * inv;
  }
}

__global__ void offsets_kernel(const int* __restrict__ cnt, int* __restrict__ off) {
  if (threadIdx.x == 0) {
    int s = 0;
#pragma unroll
    for (int e = 0; e < NEXP; ++e) { off[e] = s; s += cnt[e]; }
    off[NEXP] = s;
  }
}

// ---------------- GEMM1: H = relu(Xg @ w1^T + b1), bf16 out -----------------
// grid (HSZ/128, NTOK/128, NEXP), block 256
__global__ __launch_bounds__(256) void gemm1_kernel(
    const float* __restrict__ x, const float* __restrict__ w1,
    const float* __restrict__ b1, const int* __restrict__ cnt,
    const int* __restrict__ off, const int* __restrict__ tokl,
    unsigned short* __restrict__ Hbuf) {
  const int e = blockIdx.z;
  const int ne = cnt[e];
  const int m0 = blockIdx.y * 128;
  if (m0 >= ne) return;
  const int n0 = blockIdx.x * 128;

  __shared__ __align__(16) unsigned short As[128][32];  // tokens x k (bf16)
  __shared__ __align__(16) unsigned short Bs[128][32];  // hidden x k (bf16)

  const int tid = threadIdx.x;
  const int lane = tid & 63;
  const int wave = tid >> 6;
  const int wm = (wave >> 1) * 64;  // token offset of wave
  const int wn = (wave & 1) * 64;   // hidden offset of wave

  const int* tlist = tokl + e * NTOK;
  const float* aptr[4];
  const float* bptr[4];
  const float* bb = w1 + (size_t)e * HSZ * DMODEL + (size_t)n0 * DMODEL + (tid & 7) * 4;
#pragma unroll
  for (int i = 0; i < 4; ++i) {
    int r = (tid >> 3) + i * 32;
    int gr = m0 + r;
    int tk = tlist[(gr < ne) ? gr : 0];
    aptr[i] = x + (size_t)tk * DMODEL + (tid & 7) * 4;
    bptr[i] = bb + (size_t)r * DMODEL;
  }

  f32x4 acc[4][4];
#pragma unroll
  for (int i = 0; i < 4; ++i)
#pragma unroll
    for (int j = 0; j < 4; ++j) acc[i][j] = (f32x4){0.f, 0.f, 0.f, 0.f};

  const int fr = lane & 15;
  const int fk = (lane >> 4) * 8;

  for (int k0 = 0; k0 < DMODEL; k0 += 32) {
    __syncthreads();
#pragma unroll
    for (int i = 0; i < 4; ++i) {
      int r = (tid >> 3) + i * 32;
      int c = (tid & 7) * 4;
      float4 av = *(const float4*)(aptr[i] + k0);
      float4 bv = *(const float4*)(bptr[i] + k0);
      *(ushort4*)&As[r][c] = make_ushort4(f2bf(av.x), f2bf(av.y), f2bf(av.z), f2bf(av.w));
      *(ushort4*)&Bs[r][c] = make_ushort4(f2bf(bv.x), f2bf(bv.y), f2bf(bv.z), f2bf(bv.w));
    }
    __syncthreads();
    bf16x8 af[4], bfg[4];
#pragma unroll
    for (int i = 0; i < 4; ++i) {
      af[i]  = *(const bf16x8*)&As[wm + i * 16 + fr][fk];
      bfg[i] = *(const bf16x8*)&Bs[wn + i * 16 + fr][fk];
    }
    // operand swap: D[row=hidden quad][col=token] so lane's 4 regs are contiguous hidden
#pragma unroll
    for (int i = 0; i < 4; ++i)
#pragma unroll
      for (int j = 0; j < 4; ++j)
        acc[i][j] = __builtin_amdgcn_mfma_f32_16x16x32_bf16(bfg[j], af[i], acc[i][j], 0, 0, 0);
  }

  const int hq = (lane >> 4) * 4;
  const int toff = off[e];
#pragma unroll
  for (int i = 0; i < 4; ++i) {
    int trow = m0 + wm + i * 16 + fr;
    if (trow >= ne) continue;
    size_t hrow = (size_t)(toff + trow) * HSZ;
#pragma unroll
    for (int j = 0; j < 4; ++j) {
      int hcol = n0 + wn + j * 16 + hq;
      const float* bp = b1 + e * HSZ + hcol;
      unsigned short u[4];
#pragma unroll
      for (int r = 0; r < 4; ++r) {
        float v = acc[i][j][r] + bp[r];
        u[r] = f2bf(fmaxf(v, 0.f));
      }
      *(ushort4*)&Hbuf[hrow + hcol] = make_ushort4(u[0], u[1], u[2], u[3]);
    }
  }
}

// ---------------- GEMM2: out[tok] += w * (H @ w2^T + b2) --------------------
// grid (DMODEL/128, NTOK/128, NEXP), block 256
__global__ __launch_bounds__(256) void gemm2_kernel(
    const unsigned short* __restrict__ Hbuf, const float* __restrict__ w2,
    const float* __restrict__ b2, const int* __restrict__ cnt,
    const int* __restrict__ off, const int* __restrict__ tokl,
    const float* __restrict__ twgt, float* __restrict__ out) {
  const int e = blockIdx.z;
  const int ne = cnt[e];
  const int m0 = blockIdx.y * 128;
  if (m0 >= ne) return;
  const int n0 = blockIdx.x * 128;

  __shared__ __align__(16) unsigned short As[128][32];  // tokens x k (bf16, from Hbuf)
  __shared__ __align__(16) unsigned short Bs[128][32];  // dmodel x k (bf16)

  const int tid = threadIdx.x;
  const int lane = tid & 63;
  const int wave = tid >> 6;
  const int wm = (wave >> 1) * 64;
  const int wn = (wave & 1) * 64;
  const int toff = off[e];

  // A staging: 128 rows x 32 bf16 = 512 x 16B units, 2/thread
  const unsigned short* ap[2];
#pragma unroll
  for (int i = 0; i < 2; ++i) {
    int u = i * 256 + tid;
    int r = u >> 2;
    int gr = m0 + r;
    int rc = (gr < ne) ? gr : 0;
    ap[i] = Hbuf + (size_t)(toff + rc) * HSZ + (u & 3) * 8;
  }
  // B staging: fp32 -> bf16
  const float* bp[4];
  const float* bb = w2 + (size_t)e * DMODEL * HSZ + (size_t)n0 * HSZ + (tid & 7) * 4;
#pragma unroll
  for (int i = 0; i < 4; ++i) {
    int r = (tid >> 3) + i * 32;
    bp[i] = bb + (size_t)r * HSZ;
  }

  f32x4 acc[4][4];
#pragma unroll
  for (int i = 0; i < 4; ++i)
#pragma unroll
    for (int j = 0; j < 4; ++j) acc[i][j] = (f32x4){0.f, 0.f, 0.f, 0.f};

  const int fr = lane & 15;
  const int fk = (lane >> 4) * 8;

  for (int k0 = 0; k0 < HSZ; k0 += 32) {
    __syncthreads();
#pragma unroll
    for (int i = 0; i < 2; ++i) {
      int u = i * 256 + tid;
      int r = u >> 2, c = (u & 3) * 8;
      *(uint4*)&As[r][c] = *(const uint4*)(ap[i] + k0);
    }
#pragma unroll
    for (int i = 0; i < 4; ++i) {
      int r = (tid >> 3) + i * 32, c = (tid & 7) * 4;
      float4 bv = *(const float4*)(bp[i] + k0);
      *(ushort4*)&Bs[r][c] = make_ushort4(f2bf(bv.x), f2bf(bv.y), f2bf(bv.z), f2bf(bv.w));
    }
    __syncthreads();
    bf16x8 af[4], bfg[4];
#pragma unroll
    for (int i = 0; i < 4; ++i) {
      af[i]  = *(const bf16x8*)&As[wm + i * 16 + fr][fk];
      bfg[i] = *(const bf16x8*)&Bs[wn + i * 16 + fr][fk];
    }
#pragma unroll
    for (int i = 0; i < 4; ++i)
#pragma unroll
      for (int j = 0; j < 4; ++j)
        acc[i][j] = __builtin_amdgcn_mfma_f32_16x16x32_bf16(bfg[j], af[i], acc[i][j], 0, 0, 0);
  }

  const int* tlist = tokl + e * NTOK;
  const float* wlist = twgt + e * NTOK;
  const int dq = (lane >> 4) * 4;
#pragma unroll
  for (int i = 0; i < 4; ++i) {
    int trow = m0 + wm + i * 16 + fr;
    if (trow >= ne) continue;
    int tkn = tlist[trow];
    float wgt = wlist[trow];
    float* orow = out + (size_t)tkn * DMODEL;
#pragma unroll
    for (int j = 0; j < 4; ++j) {
      int d0 = n0 + wn + j * 16 + dq;
      const float* b2p = b2 + e * DMODEL + d0;
#pragma unroll
      for (int r = 0; r < 4; ++r)
        atomicAdd(orow + d0 + r, wgt * (acc[i][j][r] + b2p[r]));
    }
  }
}

extern "C" void kernel_launch(void* const* d_in, const int* in_sizes, int n_in,
                              void* d_out, int out_size, void* d_ws, size_t ws_size,
                              hipStream_t stream) {
  const float* x  = (const float*)d_in[0];
  const float* gw = (const float*)d_in[1];
  const float* w1 = (const float*)d_in[2];
  const float* b1 = (const float*)d_in[3];
  const float* w2 = (const float*)d_in[4];
  const float* b2 = (const float*)d_in[5];
  float* out = (float*)d_out;

  char* ws = (char*)d_ws;
  int* cnt    = (int*)ws;                                  // 8 ints
  int* off    = (int*)(ws + 64);                           // 9 ints
  int* tokl   = (int*)(ws + 128);                          // 8*4096 ints
  float* twgt = (float*)(ws + 128 + NEXP * NTOK * 4);      // 8*4096 floats
  unsigned short* Hbuf = (unsigned short*)(ws + 262400);   // [8192][4096] bf16 = 64 MB

  hipMemsetAsync(cnt, 0, 32, stream);
  hipMemsetAsync(out, 0, (size_t)NTOK * DMODEL * sizeof(float), stream);
  router_kernel<<<NTOK, 64, 0, stream>>>(x, gw, cnt, tokl, twgt);
  offsets_kernel<<<1, 64, 0, stream>>>(cnt, off);
  gemm1_kernel<<<dim3(HSZ / 128, NTOK / 128, NEXP), 256, 0, stream>>>(
      x, w1, b1, cnt, off, tokl, Hbuf);
  gemm2_kernel<<<dim3(DMODEL / 128, NTOK / 128, NEXP), 256, 0, stream>>>(
      Hbuf, w2, b2, cnt, off, tokl, twgt, out);
}

// Round 2
// 723.151 us; speedup vs baseline: 1.0783x; 1.0783x over previous
//
#include <hip/hip_runtime.h>
#include <hip/hip_bf16.h>
#include <stdint.h>

#define DMODEL 1024
#define NEXP   8
#define HSZ    4096
#define NTOK   4096   // B*S

typedef __attribute__((ext_vector_type(8))) short bf16x8;
typedef __attribute__((ext_vector_type(4))) float f32x4;

// fp32 -> bf16 round-to-nearest
__device__ __forceinline__ unsigned short f2bf(float f) {
  union { float f; unsigned u; } v; v.f = f;
  return (unsigned short)((v.u + 0x8000u) >> 16);
}

// async 16B/lane global->LDS DMA (gfx950). lds must be wave-uniform;
// HW scatters lane l -> lds + l*16.
__device__ __forceinline__ void gl2lds16(const void* g, void* lds) {
  __builtin_amdgcn_global_load_lds(
      (const __attribute__((address_space(1))) unsigned*)g,
      (__attribute__((address_space(3))) unsigned*)lds, 16, 0, 0);
}

// ---------------- fp32 -> bf16 bulk convert --------------------------------
__global__ __launch_bounds__(256) void cvt_kernel(const float* __restrict__ in,
                                                  unsigned short* __restrict__ out,
                                                  int n4) {
  int i = blockIdx.x * 256 + threadIdx.x;
  if (i < n4) {
    float4 v = ((const float4*)in)[i];
    ((ushort4*)out)[i] = make_ushort4(f2bf(v.x), f2bf(v.y), f2bf(v.z), f2bf(v.w));
  }
}

// ---------------- router: logits -> softmax -> top2 -> per-expert lists ----
__global__ void router_kernel(const float* __restrict__ x,
                              const float* __restrict__ gw,
                              int* __restrict__ cnt,
                              int* __restrict__ tokl,
                              float* __restrict__ twgt) {
  int t = blockIdx.x;
  int lane = threadIdx.x;  // 64 threads = 1 wave
  const float* xr = x + (size_t)t * DMODEL;
  float acc[NEXP];
#pragma unroll
  for (int e = 0; e < NEXP; ++e) acc[e] = 0.f;
  for (int d = lane; d < DMODEL; d += 64) {
    float xv = xr[d];
#pragma unroll
    for (int e = 0; e < NEXP; ++e) acc[e] = fmaf(xv, gw[e * DMODEL + d], acc[e]);
  }
#pragma unroll
  for (int e = 0; e < NEXP; ++e) {
#pragma unroll
    for (int o = 32; o > 0; o >>= 1) acc[e] += __shfl_down(acc[e], o);
  }
  if (lane == 0) {
    float m = acc[0];
#pragma unroll
    for (int e = 1; e < NEXP; ++e) m = fmaxf(m, acc[e]);
    float p[NEXP]; float s = 0.f;
#pragma unroll
    for (int e = 0; e < NEXP; ++e) { p[e] = __expf(acc[e] - m); s += p[e]; }
    float inv = 1.f / s;
    int i0 = 0; float b0 = p[0];
#pragma unroll
    for (int e = 1; e < NEXP; ++e) if (p[e] > b0) { b0 = p[e]; i0 = e; }
    int i1 = (i0 == 0) ? 1 : 0; float b1v = p[i1];
#pragma unroll
    for (int e = 0; e < NEXP; ++e) if (e != i0 && p[e] > b1v) { b1v = p[e]; i1 = e; }
    int p0 = atomicAdd(&cnt[i0], 1);
    tokl[i0 * NTOK + p0] = t; twgt[i0 * NTOK + p0] = b0 * inv;
    int p1 = atomicAdd(&cnt[i1], 1);
    tokl[i1 * NTOK + p1] = t; twgt[i1 * NTOK + p1] = b1v * inv;
  }
}

__global__ void offsets_kernel(const int* __restrict__ cnt, int* __restrict__ off) {
  if (threadIdx.x == 0) {
    int s = 0;
#pragma unroll
    for (int e = 0; e < NEXP; ++e) { off[e] = s; s += cnt[e]; }
    off[NEXP] = s;
  }
}

// ================= fast path: bf16 GEMMs with global_load_lds ==============
// GEMM1: H = relu(Xg @ w1^T + b1)  -- grid (HSZ/128, NTOK/128, NEXP), block 256
__global__ __launch_bounds__(256) void gemm1_bf_kernel(
    const unsigned short* __restrict__ Xbf, const unsigned short* __restrict__ W1bf,
    const float* __restrict__ b1, const int* __restrict__ cnt,
    const int* __restrict__ off, const int* __restrict__ tokl,
    unsigned short* __restrict__ Hbuf) {
  const int e = blockIdx.z;
  const int ne = cnt[e];
  const int m0 = blockIdx.y * 128;
  if (m0 >= ne) return;
  const int n0 = blockIdx.x * 128;

  __shared__ __align__(16) unsigned short As[128 * 32];  // tokens x k
  __shared__ __align__(16) unsigned short Bs[128 * 32];  // hidden x k

  const int tid = threadIdx.x;
  const int lane = tid & 63;
  const int wave = tid >> 6;
  const int wm = (wave >> 1) * 64;
  const int wn = (wave & 1) * 64;

  // staging: call c covers rows c*64+wave*16 .. +15; lane l -> row +l/4, elem col (l&3)*8
  const int srow = wave * 16 + (lane >> 2);
  const int scol = (lane & 3) * 8;
  const int* tlist = tokl + e * NTOK;
  const unsigned short* gA[2]; const unsigned short* gB[2];
  unsigned short* lA[2]; unsigned short* lB[2];
#pragma unroll
  for (int c = 0; c < 2; ++c) {
    int r = c * 64 + srow;
    int gr = m0 + r;
    int tk = tlist[(gr < ne) ? gr : 0];
    gA[c] = Xbf + (size_t)tk * DMODEL + scol;
    gB[c] = W1bf + (size_t)e * HSZ * DMODEL + (size_t)(n0 + r) * DMODEL + scol;
    lA[c] = &As[(c * 64 + wave * 16) * 32];
    lB[c] = &Bs[(c * 64 + wave * 16) * 32];
  }

  f32x4 acc[4][4];
#pragma unroll
  for (int i = 0; i < 4; ++i)
#pragma unroll
    for (int j = 0; j < 4; ++j) acc[i][j] = (f32x4){0.f, 0.f, 0.f, 0.f};

  const int fr = lane & 15;
  const int fk = (lane >> 4) * 8;

  for (int k0 = 0; k0 < DMODEL; k0 += 32) {
    __syncthreads();
#pragma unroll
    for (int c = 0; c < 2; ++c) {
      gl2lds16(gA[c] + k0, lA[c]);
      gl2lds16(gB[c] + k0, lB[c]);
    }
    __syncthreads();
    bf16x8 af[4], bfg[4];
#pragma unroll
    for (int i = 0; i < 4; ++i) {
      af[i]  = *(const bf16x8*)&As[(wm + i * 16 + fr) * 32 + fk];
      bfg[i] = *(const bf16x8*)&Bs[(wn + i * 16 + fr) * 32 + fk];
    }
    // operand swap: D[m=hidden][n=token]; lane's 4 regs = 4 contiguous hidden cols
#pragma unroll
    for (int i = 0; i < 4; ++i)
#pragma unroll
      for (int j = 0; j < 4; ++j)
        acc[i][j] = __builtin_amdgcn_mfma_f32_16x16x32_bf16(bfg[j], af[i], acc[i][j], 0, 0, 0);
  }

  const int hq = (lane >> 4) * 4;
  const int toff = off[e];
#pragma unroll
  for (int i = 0; i < 4; ++i) {
    int trow = m0 + wm + i * 16 + fr;
    if (trow >= ne) continue;
    size_t hrow = (size_t)(toff + trow) * HSZ;
#pragma unroll
    for (int j = 0; j < 4; ++j) {
      int hcol = n0 + wn + j * 16 + hq;
      const float* bp = b1 + e * HSZ + hcol;
      unsigned short u[4];
#pragma unroll
      for (int r = 0; r < 4; ++r)
        u[r] = f2bf(fmaxf(acc[i][j][r] + bp[r], 0.f));
      *(ushort4*)&Hbuf[hrow + hcol] = make_ushort4(u[0], u[1], u[2], u[3]);
    }
  }
}

// GEMM2: out[tok] += w * (H @ w2^T + b2) -- grid (DMODEL/128, NTOK/128, NEXP)
__global__ __launch_bounds__(256) void gemm2_bf_kernel(
    const unsigned short* __restrict__ Hbuf, const unsigned short* __restrict__ W2bf,
    const float* __restrict__ b2, const int* __restrict__ cnt,
    const int* __restrict__ off, const int* __restrict__ tokl,
    const float* __restrict__ twgt, float* __restrict__ out) {
  const int e = blockIdx.z;
  const int ne = cnt[e];
  const int m0 = blockIdx.y * 128;
  if (m0 >= ne) return;
  const int n0 = blockIdx.x * 128;

  __shared__ __align__(16) unsigned short As[128 * 32];
  __shared__ __align__(16) unsigned short Bs[128 * 32];

  const int tid = threadIdx.x;
  const int lane = tid & 63;
  const int wave = tid >> 6;
  const int wm = (wave >> 1) * 64;
  const int wn = (wave & 1) * 64;
  const int toff = off[e];

  const int srow = wave * 16 + (lane >> 2);
  const int scol = (lane & 3) * 8;
  const unsigned short* gA[2]; const unsigned short* gB[2];
  unsigned short* lA[2]; unsigned short* lB[2];
#pragma unroll
  for (int c = 0; c < 2; ++c) {
    int r = c * 64 + srow;
    int gr = m0 + r;
    int rc = (gr < ne) ? gr : 0;
    gA[c] = Hbuf + (size_t)(toff + rc) * HSZ + scol;
    gB[c] = W2bf + (size_t)e * DMODEL * HSZ + (size_t)(n0 + r) * HSZ + scol;
    lA[c] = &As[(c * 64 + wave * 16) * 32];
    lB[c] = &Bs[(c * 64 + wave * 16) * 32];
  }

  f32x4 acc[4][4];
#pragma unroll
  for (int i = 0; i < 4; ++i)
#pragma unroll
    for (int j = 0; j < 4; ++j) acc[i][j] = (f32x4){0.f, 0.f, 0.f, 0.f};

  const int fr = lane & 15;
  const int fk = (lane >> 4) * 8;

  for (int k0 = 0; k0 < HSZ; k0 += 32) {
    __syncthreads();
#pragma unroll
    for (int c = 0; c < 2; ++c) {
      gl2lds16(gA[c] + k0, lA[c]);
      gl2lds16(gB[c] + k0, lB[c]);
    }
    __syncthreads();
    bf16x8 af[4], bfg[4];
#pragma unroll
    for (int i = 0; i < 4; ++i) {
      af[i]  = *(const bf16x8*)&As[(wm + i * 16 + fr) * 32 + fk];
      bfg[i] = *(const bf16x8*)&Bs[(wn + i * 16 + fr) * 32 + fk];
    }
#pragma unroll
    for (int i = 0; i < 4; ++i)
#pragma unroll
      for (int j = 0; j < 4; ++j)
        acc[i][j] = __builtin_amdgcn_mfma_f32_16x16x32_bf16(bfg[j], af[i], acc[i][j], 0, 0, 0);
  }

  const int* tlist = tokl + e * NTOK;
  const float* wlist = twgt + e * NTOK;
  const int dq = (lane >> 4) * 4;
#pragma unroll
  for (int i = 0; i < 4; ++i) {
    int trow = m0 + wm + i * 16 + fr;
    if (trow >= ne) continue;
    int tkn = tlist[trow];
    float wgt = wlist[trow];
    float* orow = out + (size_t)tkn * DMODEL;
#pragma unroll
    for (int j = 0; j < 4; ++j) {
      int d0 = n0 + wn + j * 16 + dq;
      const float* b2p = b2 + e * DMODEL + d0;
#pragma unroll
      for (int r = 0; r < 4; ++r)
        atomicAdd(orow + d0 + r, wgt * (acc[i][j][r] + b2p[r]));
    }
  }
}

// ================= fallback path (R1): fp32 loads, convert in staging ======
__global__ __launch_bounds__(256) void gemm1_f32_kernel(
    const float* __restrict__ x, const float* __restrict__ w1,
    const float* __restrict__ b1, const int* __restrict__ cnt,
    const int* __restrict__ off, const int* __restrict__ tokl,
    unsigned short* __restrict__ Hbuf) {
  const int e = blockIdx.z;
  const int ne = cnt[e];
  const int m0 = blockIdx.y * 128;
  if (m0 >= ne) return;
  const int n0 = blockIdx.x * 128;
  __shared__ __align__(16) unsigned short As[128][32];
  __shared__ __align__(16) unsigned short Bs[128][32];
  const int tid = threadIdx.x;
  const int lane = tid & 63;
  const int wave = tid >> 6;
  const int wm = (wave >> 1) * 64;
  const int wn = (wave & 1) * 64;
  const int* tlist = tokl + e * NTOK;
  const float* aptr[4]; const float* bptr[4];
  const float* bb = w1 + (size_t)e * HSZ * DMODEL + (size_t)n0 * DMODEL + (tid & 7) * 4;
#pragma unroll
  for (int i = 0; i < 4; ++i) {
    int r = (tid >> 3) + i * 32;
    int gr = m0 + r;
    int tk = tlist[(gr < ne) ? gr : 0];
    aptr[i] = x + (size_t)tk * DMODEL + (tid & 7) * 4;
    bptr[i] = bb + (size_t)r * DMODEL;
  }
  f32x4 acc[4][4];
#pragma unroll
  for (int i = 0; i < 4; ++i)
#pragma unroll
    for (int j = 0; j < 4; ++j) acc[i][j] = (f32x4){0.f, 0.f, 0.f, 0.f};
  const int fr = lane & 15;
  const int fk = (lane >> 4) * 8;
  for (int k0 = 0; k0 < DMODEL; k0 += 32) {
    __syncthreads();
#pragma unroll
    for (int i = 0; i < 4; ++i) {
      int r = (tid >> 3) + i * 32, c = (tid & 7) * 4;
      float4 av = *(const float4*)(aptr[i] + k0);
      float4 bv = *(const float4*)(bptr[i] + k0);
      *(ushort4*)&As[r][c] = make_ushort4(f2bf(av.x), f2bf(av.y), f2bf(av.z), f2bf(av.w));
      *(ushort4*)&Bs[r][c] = make_ushort4(f2bf(bv.x), f2bf(bv.y), f2bf(bv.z), f2bf(bv.w));
    }
    __syncthreads();
    bf16x8 af[4], bfg[4];
#pragma unroll
    for (int i = 0; i < 4; ++i) {
      af[i]  = *(const bf16x8*)&As[wm + i * 16 + fr][fk];
      bfg[i] = *(const bf16x8*)&Bs[wn + i * 16 + fr][fk];
    }
#pragma unroll
    for (int i = 0; i < 4; ++i)
#pragma unroll
      for (int j = 0; j < 4; ++j)
        acc[i][j] = __builtin_amdgcn_mfma_f32_16x16x32_bf16(bfg[j], af[i], acc[i][j], 0, 0, 0);
  }
  const int hq = (lane >> 4) * 4;
  const int toff = off[e];
#pragma unroll
  for (int i = 0; i < 4; ++i) {
    int trow = m0 + wm + i * 16 + fr;
    if (trow >= ne) continue;
    size_t hrow = (size_t)(toff + trow) * HSZ;
#pragma unroll
    for (int j = 0; j < 4; ++j) {
      int hcol = n0 + wn + j * 16 + hq;
      const float* bp = b1 + e * HSZ + hcol;
      unsigned short u[4];
#pragma unroll
      for (int r = 0; r < 4; ++r)
        u[r] = f2bf(fmaxf(acc[i][j][r] + bp[r], 0.f));
      *(ushort4*)&Hbuf[hrow + hcol] = make_ushort4(u[0], u[1], u[2], u[3]);
    }
  }
}

__global__ __launch_bounds__(256) void gemm2_f32_kernel(
    const unsigned short* __restrict__ Hbuf, const float* __restrict__ w2,
    const float* __restrict__ b2, const int* __restrict__ cnt,
    const int* __restrict__ off, const int* __restrict__ tokl,
    const float* __restrict__ twgt, float* __restrict__ out) {
  const int e = blockIdx.z;
  const int ne = cnt[e];
  const int m0 = blockIdx.y * 128;
  if (m0 >= ne) return;
  const int n0 = blockIdx.x * 128;
  __shared__ __align__(16) unsigned short As[128][32];
  __shared__ __align__(16) unsigned short Bs[128][32];
  const int tid = threadIdx.x;
  const int lane = tid & 63;
  const int wave = tid >> 6;
  const int wm = (wave >> 1) * 64;
  const int wn = (wave & 1) * 64;
  const int toff = off[e];
  const unsigned short* ap[2];
#pragma unroll
  for (int i = 0; i < 2; ++i) {
    int u = i * 256 + tid;
    int r = u >> 2;
    int gr = m0 + r;
    int rc = (gr < ne) ? gr : 0;
    ap[i] = Hbuf + (size_t)(toff + rc) * HSZ + (u & 3) * 8;
  }
  const float* bp[4];
  const float* bb = w2 + (size_t)e * DMODEL * HSZ + (size_t)n0 * HSZ + (tid & 7) * 4;
#pragma unroll
  for (int i = 0; i < 4; ++i) {
    int r = (tid >> 3) + i * 32;
    bp[i] = bb + (size_t)r * HSZ;
  }
  f32x4 acc[4][4];
#pragma unroll
  for (int i = 0; i < 4; ++i)
#pragma unroll
    for (int j = 0; j < 4; ++j) acc[i][j] = (f32x4){0.f, 0.f, 0.f, 0.f};
  const int fr = lane & 15;
  const int fk = (lane >> 4) * 8;
  for (int k0 = 0; k0 < HSZ; k0 += 32) {
    __syncthreads();
#pragma unroll
    for (int i = 0; i < 2; ++i) {
      int u = i * 256 + tid;
      int r = u >> 2, c = (u & 3) * 8;
      *(uint4*)&As[r][c] = *(const uint4*)(ap[i] + k0);
    }
#pragma unroll
    for (int i = 0; i < 4; ++i) {
      int r = (tid >> 3) + i * 32, c = (tid & 7) * 4;
      float4 bv = *(const float4*)(bp[i] + k0);
      *(ushort4*)&Bs[r][c] = make_ushort4(f2bf(bv.x), f2bf(bv.y), f2bf(bv.z), f2bf(bv.w));
    }
    __syncthreads();
    bf16x8 af[4], bfg[4];
#pragma unroll
    for (int i = 0; i < 4; ++i) {
      af[i]  = *(const bf16x8*)&As[wm + i * 16 + fr][fk];
      bfg[i] = *(const bf16x8*)&Bs[wn + i * 16 + fr][fk];
    }
#pragma unroll
    for (int i = 0; i < 4; ++i)
#pragma unroll
      for (int j = 0; j < 4; ++j)
        acc[i][j] = __builtin_amdgcn_mfma_f32_16x16x32_bf16(bfg[j], af[i], acc[i][j], 0, 0, 0);
  }
  const int* tlist = tokl + e * NTOK;
  const float* wlist = twgt + e * NTOK;
  const int dq = (lane >> 4) * 4;
#pragma unroll
  for (int i = 0; i < 4; ++i) {
    int trow = m0 + wm + i * 16 + fr;
    if (trow >= ne) continue;
    int tkn = tlist[trow];
    float wgt = wlist[trow];
    float* orow = out + (size_t)tkn * DMODEL;
#pragma unroll
    for (int j = 0; j < 4; ++j) {
      int d0 = n0 + wn + j * 16 + dq;
      const float* b2p = b2 + e * DMODEL + d0;
#pragma unroll
      for (int r = 0; r < 4; ++r)
        atomicAdd(orow + d0 + r, wgt * (acc[i][j][r] + b2p[r]));
    }
  }
}

extern "C" void kernel_launch(void* const* d_in, const int* in_sizes, int n_in,
                              void* d_out, int out_size, void* d_ws, size_t ws_size,
                              hipStream_t stream) {
  const float* x  = (const float*)d_in[0];
  const float* gw = (const float*)d_in[1];
  const float* w1 = (const float*)d_in[2];
  const float* b1 = (const float*)d_in[3];
  const float* w2 = (const float*)d_in[4];
  const float* b2 = (const float*)d_in[5];
  float* out = (float*)d_out;

  char* ws = (char*)d_ws;
  int* cnt    = (int*)ws;                                  // 8 ints
  int* off    = (int*)(ws + 64);                           // 9 ints
  int* tokl   = (int*)(ws + 128);                          // 8*4096 ints = 128 KB
  float* twgt = (float*)(ws + 128 + NEXP * NTOK * 4);      // 128 KB

  constexpr size_t OFF_XBF  = 262144;                                   // 256 KB
  constexpr size_t OFF_W1BF = OFF_XBF  + (size_t)NTOK * DMODEL * 2;     // +8 MB
  constexpr size_t OFF_W2BF = OFF_W1BF + (size_t)NEXP * HSZ * DMODEL * 2;  // +64 MB
  constexpr size_t OFF_HBUF = OFF_W2BF + (size_t)NEXP * DMODEL * HSZ * 2;  // +64 MB
  constexpr size_t WS_NEED  = OFF_HBUF + (size_t)2 * NTOK * HSZ * 2;       // +64 MB ~200 MB

  hipMemsetAsync(cnt, 0, 32, stream);
  hipMemsetAsync(out, 0, (size_t)NTOK * DMODEL * sizeof(float), stream);
  router_kernel<<<NTOK, 64, 0, stream>>>(x, gw, cnt, tokl, twgt);
  offsets_kernel<<<1, 64, 0, stream>>>(cnt, off);

  if (ws_size >= WS_NEED) {
    unsigned short* Xbf  = (unsigned short*)(ws + OFF_XBF);
    unsigned short* W1bf = (unsigned short*)(ws + OFF_W1BF);
    unsigned short* W2bf = (unsigned short*)(ws + OFF_W2BF);
    unsigned short* Hbuf = (unsigned short*)(ws + OFF_HBUF);
    const int nx = NTOK * DMODEL / 4;                 // 1,048,576
    const int nw = NEXP * HSZ * DMODEL / 4;           // 8,388,608
    cvt_kernel<<<(nx + 255) / 256, 256, 0, stream>>>(x, Xbf, nx);
    cvt_kernel<<<(nw + 255) / 256, 256, 0, stream>>>(w1, W1bf, nw);
    cvt_kernel<<<(nw + 255) / 256, 256, 0, stream>>>(w2, W2bf, nw);
    gemm1_bf_kernel<<<dim3(HSZ / 128, NTOK / 128, NEXP), 256, 0, stream>>>(
        Xbf, W1bf, b1, cnt, off, tokl, Hbuf);
    gemm2_bf_kernel<<<dim3(DMODEL / 128, NTOK / 128, NEXP), 256, 0, stream>>>(
        Hbuf, W2bf, b2, cnt, off, tokl, twgt, out);
  } else {
    unsigned short* Hbuf = (unsigned short*)(ws + OFF_XBF);  // 64 MB fallback layout
    gemm1_f32_kernel<<<dim3(HSZ / 128, NTOK / 128, NEXP), 256, 0, stream>>>(
        x, w1, b1, cnt, off, tokl, Hbuf);
    gemm2_f32_kernel<<<dim3(DMODEL / 128, NTOK / 128, NEXP), 256, 0, stream>>>(
        Hbuf, w2, b2, cnt, off, tokl, twgt, out);
  }
}